// Round 10
// baseline (41.543 us; speedup 1.0000x reference)
//
#include <hip/hip_runtime.h>
#include <hip/hip_bf16.h>
#include <math.h>

#define NTOK 4096
#define CDIM 256
#define NH   8
#define HD   32
#define SCALE 0.17677669529663687f  // 32^-0.5

typedef __attribute__((ext_vector_type(8))) short bf16x8;
typedef __attribute__((ext_vector_type(4))) short short4v;
typedef __attribute__((ext_vector_type(4))) float f32x4;

__device__ inline short f2b(float f) {
  union { __hip_bfloat16 h; short s; } u;
  u.h = __float2bfloat16(f);
  return u.s;
}
__device__ inline short4v pack4(f32x4 v) {
  short4v o; o[0] = f2b(v[0]); o[1] = f2b(v[1]); o[2] = f2b(v[2]); o[3] = f2b(v[3]);
  return o;
}

// ---------------- prep: bf16 conversions + weight transposes ----------------
__global__ __launch_bounds__(256) void prep_kernel(
    const float* __restrict__ qkv, const float* __restrict__ qpos,
    const float* __restrict__ Wq, const float* __restrict__ Wkv,
    const float* __restrict__ Wp,
    short* __restrict__ Xq, short* __restrict__ X,
    short* __restrict__ WT, short* __restrict__ WpT)
{
  const int b = blockIdx.x, t = threadIdx.x;
  if (b < 1024) {
    const int i4 = (b * 256 + t) * 4;
    float4 a = *(const float4*)(qkv + i4);
    float4 p = *(const float4*)(qpos + i4);
    short4v xo, qo;
    xo[0] = f2b(a.x); xo[1] = f2b(a.y); xo[2] = f2b(a.z); xo[3] = f2b(a.w);
    qo[0] = f2b(a.x + p.x); qo[1] = f2b(a.y + p.y); qo[2] = f2b(a.z + p.z); qo[3] = f2b(a.w + p.w);
    *(short4v*)(X + i4)  = xo;
    *(short4v*)(Xq + i4) = qo;
  } else {
    const int gid = (b - 1024) * 256 + t;   // 0..65535
    const int c  = gid & 1023;
    const int k4 = (gid >> 10) * 4;
    short4v o;
    if (c < 768) {
      #pragma unroll
      for (int j = 0; j < 4; ++j) {
        int k = k4 + j;
        float v = (c < 256) ? Wq[(size_t)k * 256 + c] * SCALE
                            : Wkv[(size_t)k * 512 + (c - 256)];
        o[j] = f2b(v);
      }
      *(short4v*)(WT + (size_t)c * 256 + k4) = o;
    } else {
      const int cc = c - 768;
      #pragma unroll
      for (int j = 0; j < 4; ++j) o[j] = f2b(Wp[(size_t)(k4 + j) * 256 + cc]);
      *(short4v*)(WpT + (size_t)cc * 256 + k4) = o;
    }
  }
}

// ---------------- fused QKV projection (MFMA, 64x64 tiles) ----------------
// bx 0..3: q -> qb[n][c] (swapped); bx 4..7: k -> khp[h][tile][slot][d]
// (per-tile key-permuted); bx 8..11: v -> vblk[h][tile][d][k] (tile-blocked)
__global__ __launch_bounds__(256) void gemm_qkv(
    const short* __restrict__ Xq, const short* __restrict__ X,
    const short* __restrict__ WT,
    short* __restrict__ qb, short* __restrict__ khp, short* __restrict__ vblk)
{
  __shared__ short Al[64][40];
  __shared__ short Wl[64][40];
  const int bx = blockIdx.x;
  const int n0 = blockIdx.y * 64;
  const int c0 = bx * 64;                   // row range in WT [0,768)
  const int tid = threadIdx.x;
  const int w = tid >> 6, l = tid & 63, lg = l >> 4, lr = l & 15;
  const int wc = w & 1, wn = w >> 1;
  const short* A = (bx < 4) ? Xq : X;

  f32x4 acc[2][2];
  #pragma unroll
  for (int i = 0; i < 2; ++i)
    #pragma unroll
    for (int j = 0; j < 2; ++j) acc[i][j] = (f32x4){0.f, 0.f, 0.f, 0.f};

  for (int kt = 0; kt < 256; kt += 32) {
    __syncthreads();
    {
      int row = tid >> 2, seg = tid & 3;
      *(bf16x8*)&Al[row][seg * 8] = *(const bf16x8*)(A  + (size_t)(n0 + row) * 256 + kt + seg * 8);
      *(bf16x8*)&Wl[row][seg * 8] = *(const bf16x8*)(WT + (size_t)(c0 + row) * 256 + kt + seg * 8);
    }
    __syncthreads();
    bf16x8 wf[2], xf[2];
    #pragma unroll
    for (int ci = 0; ci < 2; ++ci) wf[ci] = *(bf16x8*)&Wl[wc * 32 + ci * 16 + lr][lg * 8];
    #pragma unroll
    for (int ni = 0; ni < 2; ++ni) xf[ni] = *(bf16x8*)&Al[wn * 32 + ni * 16 + lr][lg * 8];
    if (bx < 8) {
      #pragma unroll
      for (int ci = 0; ci < 2; ++ci)
        #pragma unroll
        for (int ni = 0; ni < 2; ++ni)
          acc[ci][ni] = __builtin_amdgcn_mfma_f32_16x16x32_bf16(wf[ci], xf[ni], acc[ci][ni], 0, 0, 0);
    } else {
      #pragma unroll
      for (int ci = 0; ci < 2; ++ci)
        #pragma unroll
        for (int ni = 0; ni < 2; ++ni)
          acc[ci][ni] = __builtin_amdgcn_mfma_f32_16x16x32_bf16(xf[ni], wf[ci], acc[ci][ni], 0, 0, 0);
    }
  }

  if (bx < 4) {
    const int cl0 = bx * 64;
    #pragma unroll
    for (int ci = 0; ci < 2; ++ci)
      #pragma unroll
      for (int ni = 0; ni < 2; ++ni) {
        int c = cl0 + wc * 32 + ci * 16 + lg * 4;
        int n = n0 + wn * 32 + ni * 16 + lr;
        *(short4v*)(qb + (size_t)n * 256 + c) = pack4(acc[ci][ni]);
      }
  } else if (bx < 8) {
    // k: khp[h][tile][slot][d], slot = ((k>>2)&1)*16 + (k>>3)*4 + (k&3)
    const int cl0 = (bx - 4) * 64;
    #pragma unroll
    for (int ci = 0; ci < 2; ++ci)
      #pragma unroll
      for (int ni = 0; ni < 2; ++ni) {
        int c = cl0 + wc * 32 + ci * 16 + lg * 4;
        int n = n0 + wn * 32 + ni * 16 + lr;
        int hh = c >> 5, d = c & 31;
        int tt = n >> 5, k = n & 31;
        int s = ((k >> 2) & 1) * 16 + (k >> 3) * 4 + (k & 3);
        *(short4v*)(khp + (((size_t)hh * 128 + tt) * 32 + s) * 32 + d) = pack4(acc[ci][ni]);
      }
  } else {
    // v: vblk[h][tile][d][k]
    const int cv0 = (bx - 8) * 64;
    #pragma unroll
    for (int ci = 0; ci < 2; ++ci)
      #pragma unroll
      for (int ni = 0; ni < 2; ++ni) {
        int c = cv0 + wc * 32 + ci * 16 + lr;
        int n = n0 + wn * 32 + ni * 16 + lg * 4;
        int hh = c >> 5, d = c & 31;
        int tt = n >> 5, k = n & 31;
        *(short4v*)(vblk + (((size_t)hh * 128 + tt) * 32 + d) * 32 + k) = pack4(acc[ci][ni]);
      }
  }
}

// ---------------- attn8: 64-key chunks, deep prefetch, setprio ----------------
// block = (32-query tile, head); 4 waves split the key range in 64-key chunks.
// Per chunk: 8 contiguous 1KB loads (next chunk, in flight across the whole
// body), 8 QK + 8 PV MFMAs, interior chunks skip masking entirely.
__global__ __launch_bounds__(256) void attn8(
    const short* __restrict__ qb, const short* __restrict__ khp,
    const short* __restrict__ vblk, const int* __restrict__ cu,
    short* __restrict__ featb)
{
  __shared__ float red[4][64][18];
  const int tid = threadIdx.x;
  const int w = tid >> 6, l = tid & 63, lg = l >> 4, lr = l & 15;
  const int bid = blockIdx.x;                       // 1024 blocks (8 | 1024)
  const int lid = ((bid & 7) << 7) | (bid >> 3);    // bijective XCD swizzle
  const int h = lid & 7, t32 = lid >> 3;
  const int n0 = t32 * 32;

  int cs[9];
  #pragma unroll
  for (int i = 0; i < 9; ++i) cs[i] = cu[i];

  const int qn0 = n0 + lr, qn1 = n0 + 16 + lr;
  int g0 = 0, g1 = 0, sg0 = 0, sgL = 0;
  #pragma unroll
  for (int j = 1; j <= 8; ++j) {
    g0  += (cs[j] <= qn0);
    g1  += (cs[j] <= qn1);
    sg0 += (cs[j] <= n0);
    sgL += (cs[j] <= n0 + 31);
  }
  const int kbeg0 = cs[g0], kend0 = cs[g0 + 1];
  const int kbeg1 = cs[g1], kend1 = cs[g1 + 1];
  const bool oneSeg = (sg0 == sgL);
  const int kbB = cs[sg0], keB = cs[sgL + 1];
  const int lo = kbB & ~31;
  const int hi = keB;
  const int t0 = lo >> 5;
  const int nT = (hi - lo + 31) >> 5;       // 32-key tiles
  const int nC = (nT + 1) >> 1;             // 64-key chunks
  const int qC = (nC + 3) >> 2;
  const int ic0 = w * qC;
  const int ic1 = (ic0 + qC < nC) ? (ic0 + qC) : nC;

  const bf16x8 qf0 = *(const bf16x8*)(qb + (size_t)qn0 * 256 + h * 32 + lg * 8);
  const bf16x8 qf1 = *(const bf16x8*)(qb + (size_t)qn1 * 256 + h * 32 + lg * 8);
  const short* kL = khp  + (size_t)h * 131072 + lr * 32 + lg * 8;
  const short* vL = vblk + (size_t)h * 131072 + lr * 32 + lg * 8;

  f32x4 acc00 = {0.f,0.f,0.f,0.f}, acc01 = {0.f,0.f,0.f,0.f};
  f32x4 acc10 = {0.f,0.f,0.f,0.f}, acc11 = {0.f,0.f,0.f,0.f};
  float Lp0 = 0.f, Lp1 = 0.f;
  const f32x4 z4 = {0.f, 0.f, 0.f, 0.f};

  if (ic0 < ic1) {
    // tile indices for chunk ic: tA = t0+2ic, tB = tA+1 (clamped to stay in-buffer)
    int tA = t0 + 2 * ic0;
    int tB = (tA + 1 < 128) ? (tA + 1) : 127;
    const short* kpA = kL + (size_t)tA * 1024;
    const short* vpA = vL + (size_t)tA * 1024;
    const short* kpB = kL + (size_t)tB * 1024;
    const short* vpB = vL + (size_t)tB * 1024;
    bf16x8 ka0 = *(const bf16x8*)(kpA);
    bf16x8 kc0 = *(const bf16x8*)(kpA + 512);
    bf16x8 va0 = *(const bf16x8*)(vpA);
    bf16x8 vb0 = *(const bf16x8*)(vpA + 512);
    bf16x8 ka1 = *(const bf16x8*)(kpB);
    bf16x8 kc1 = *(const bf16x8*)(kpB + 512);
    bf16x8 va1 = *(const bf16x8*)(vpB);
    bf16x8 vb1 = *(const bf16x8*)(vpB + 512);

    for (int ic = ic0; ic < ic1; ++ic) {
      // prefetch next chunk (8 loads in flight across this body)
      const int icn = (ic + 1 < ic1) ? (ic + 1) : ic;
      int tAn = t0 + 2 * icn;
      int tBn = (tAn + 1 < 128) ? (tAn + 1) : 127;
      const short* kpAn = kL + (size_t)tAn * 1024;
      const short* vpAn = vL + (size_t)tAn * 1024;
      const short* kpBn = kL + (size_t)tBn * 1024;
      const short* vpBn = vL + (size_t)tBn * 1024;
      bf16x8 nka0 = *(const bf16x8*)(kpAn);
      bf16x8 nkc0 = *(const bf16x8*)(kpAn + 512);
      bf16x8 nva0 = *(const bf16x8*)(vpAn);
      bf16x8 nvb0 = *(const bf16x8*)(vpAn + 512);
      bf16x8 nka1 = *(const bf16x8*)(kpBn);
      bf16x8 nkc1 = *(const bf16x8*)(kpBn + 512);
      bf16x8 nva1 = *(const bf16x8*)(vpBn);
      bf16x8 nvb1 = *(const bf16x8*)(vpBn + 512);

      __builtin_amdgcn_s_setprio(1);
      f32x4 s00a = __builtin_amdgcn_mfma_f32_16x16x32_bf16(ka0, qf0, z4, 0, 0, 0);
      f32x4 s01a = __builtin_amdgcn_mfma_f32_16x16x32_bf16(kc0, qf0, z4, 0, 0, 0);
      f32x4 s10a = __builtin_amdgcn_mfma_f32_16x16x32_bf16(ka0, qf1, z4, 0, 0, 0);
      f32x4 s11a = __builtin_amdgcn_mfma_f32_16x16x32_bf16(kc0, qf1, z4, 0, 0, 0);
      f32x4 s00b = __builtin_amdgcn_mfma_f32_16x16x32_bf16(ka1, qf0, z4, 0, 0, 0);
      f32x4 s01b = __builtin_amdgcn_mfma_f32_16x16x32_bf16(kc1, qf0, z4, 0, 0, 0);
      f32x4 s10b = __builtin_amdgcn_mfma_f32_16x16x32_bf16(ka1, qf1, z4, 0, 0, 0);
      f32x4 s11b = __builtin_amdgcn_mfma_f32_16x16x32_bf16(kc1, qf1, z4, 0, 0, 0);

      const int ktA = (t0 + 2 * ic) * 32;
      bf16x8 pf0a, pf1a, pf0b, pf1b;
      if (oneSeg & (ktA >= kbB) & (ktA + 64 <= keB)) {
        // fully interior 64-key chunk: no masking
        #pragma unroll
        for (int r = 0; r < 4; ++r) {
          float p00a = __expf(s00a[r]), p01a = __expf(s01a[r]);
          float p10a = __expf(s10a[r]), p11a = __expf(s11a[r]);
          float p00b = __expf(s00b[r]), p01b = __expf(s01b[r]);
          float p10b = __expf(s10b[r]), p11b = __expf(s11b[r]);
          Lp0 += (p00a + p01a) + (p00b + p01b);
          Lp1 += (p10a + p11a) + (p10b + p11b);
          pf0a[r] = f2b(p00a); pf0a[4 + r] = f2b(p01a);
          pf1a[r] = f2b(p10a); pf1a[4 + r] = f2b(p11a);
          pf0b[r] = f2b(p00b); pf0b[4 + r] = f2b(p01b);
          pf1b[r] = f2b(p10b); pf1b[4 + r] = f2b(p11b);
        }
      } else {
        const int kga = ktA + lg * 8;
        const int kgb = ktA + 32 + lg * 8;
        #pragma unroll
        for (int r = 0; r < 4; ++r) {
          int ka_ = kga + r, kb_ = kga + 4 + r;
          int kc_ = kgb + r, kd_ = kgb + 4 + r;
          float p00a = ((ka_ >= kbeg0) & (ka_ < kend0)) ? __expf(s00a[r]) : 0.f;
          float p01a = ((kb_ >= kbeg0) & (kb_ < kend0)) ? __expf(s01a[r]) : 0.f;
          float p10a = ((ka_ >= kbeg1) & (ka_ < kend1)) ? __expf(s10a[r]) : 0.f;
          float p11a = ((kb_ >= kbeg1) & (kb_ < kend1)) ? __expf(s11a[r]) : 0.f;
          float p00b = ((kc_ >= kbeg0) & (kc_ < kend0)) ? __expf(s00b[r]) : 0.f;
          float p01b = ((kd_ >= kbeg0) & (kd_ < kend0)) ? __expf(s01b[r]) : 0.f;
          float p10b = ((kc_ >= kbeg1) & (kc_ < kend1)) ? __expf(s10b[r]) : 0.f;
          float p11b = ((kd_ >= kbeg1) & (kd_ < kend1)) ? __expf(s11b[r]) : 0.f;
          Lp0 += (p00a + p01a) + (p00b + p01b);
          Lp1 += (p10a + p11a) + (p10b + p11b);
          pf0a[r] = f2b(p00a); pf0a[4 + r] = f2b(p01a);
          pf1a[r] = f2b(p10a); pf1a[4 + r] = f2b(p11a);
          pf0b[r] = f2b(p00b); pf0b[4 + r] = f2b(p01b);
          pf1b[r] = f2b(p10b); pf1b[4 + r] = f2b(p11b);
        }
      }
      acc00 = __builtin_amdgcn_mfma_f32_16x16x32_bf16(pf0a, va0, acc00, 0, 0, 0);
      acc01 = __builtin_amdgcn_mfma_f32_16x16x32_bf16(pf0a, vb0, acc01, 0, 0, 0);
      acc10 = __builtin_amdgcn_mfma_f32_16x16x32_bf16(pf1a, va0, acc10, 0, 0, 0);
      acc11 = __builtin_amdgcn_mfma_f32_16x16x32_bf16(pf1a, vb0, acc11, 0, 0, 0);
      acc00 = __builtin_amdgcn_mfma_f32_16x16x32_bf16(pf0b, va1, acc00, 0, 0, 0);
      acc01 = __builtin_amdgcn_mfma_f32_16x16x32_bf16(pf0b, vb1, acc01, 0, 0, 0);
      acc10 = __builtin_amdgcn_mfma_f32_16x16x32_bf16(pf1b, va1, acc10, 0, 0, 0);
      acc11 = __builtin_amdgcn_mfma_f32_16x16x32_bf16(pf1b, vb1, acc11, 0, 0, 0);
      __builtin_amdgcn_s_setprio(0);

      ka0 = nka0; kc0 = nkc0; va0 = nva0; vb0 = nvb0;
      ka1 = nka1; kc1 = nkc1; va1 = nva1; vb1 = nvb1;
    }
  }

  // merge the 4 key-splits: pure sum (fixed-max softmax)
  #pragma unroll
  for (int r = 0; r < 4; ++r) {
    red[w][l][r]      = acc00[r];
    red[w][l][4 + r]  = acc01[r];
    red[w][l][8 + r]  = acc10[r];
    red[w][l][12 + r] = acc11[r];
  }
  red[w][l][16] = Lp0;
  red[w][l][17] = Lp1;
  __syncthreads();
  if (w == 0) {
    float a00[4] = {0,0,0,0}, a01[4] = {0,0,0,0};
    float a10[4] = {0,0,0,0}, a11[4] = {0,0,0,0};
    float Ls0 = 0.f, Ls1 = 0.f;
    #pragma unroll
    for (int wv = 0; wv < 4; ++wv) {
      #pragma unroll
      for (int r = 0; r < 4; ++r) {
        a00[r] += red[wv][l][r];      a01[r] += red[wv][l][4 + r];
        a10[r] += red[wv][l][8 + r];  a11[r] += red[wv][l][12 + r];
      }
      Ls0 += red[wv][l][16];
      Ls1 += red[wv][l][17];
    }
    Ls0 += __shfl_xor(Ls0, 16); Ls0 += __shfl_xor(Ls0, 32);
    Ls1 += __shfl_xor(Ls1, 16); Ls1 += __shfl_xor(Ls1, 32);
    float inv0 = 1.f / Ls0, inv1 = 1.f / Ls1;
    #pragma unroll
    for (int r = 0; r < 4; ++r) {
      float i0 = __shfl(inv0, lg * 4 + r);
      float i1 = __shfl(inv1, lg * 4 + r);
      int na = n0 + lg * 4 + r;
      int nb = n0 + 16 + lg * 4 + r;
      featb[(size_t)na * 256 + h * 32 + lr]      = f2b(a00[r] * i0);
      featb[(size_t)na * 256 + h * 32 + 16 + lr] = f2b(a01[r] * i0);
      featb[(size_t)nb * 256 + h * 32 + lr]      = f2b(a10[r] * i1);
      featb[(size_t)nb * 256 + h * 32 + 16 + lr] = f2b(a11[r] * i1);
    }
  }
}

// ---------------- output projection (MFMA, 64x64 tiles, swapped) + bias ----------------
__global__ __launch_bounds__(256) void gemm_out(
    const short* __restrict__ Fb, const short* __restrict__ WpT,
    const float* __restrict__ bias, float* __restrict__ out)
{
  __shared__ short Al[64][40];
  __shared__ short Wl[64][40];
  const int c0 = blockIdx.x * 64;
  const int n0 = blockIdx.y * 64;
  const int tid = threadIdx.x;
  const int w = tid >> 6, l = tid & 63, lg = l >> 4, lr = l & 15;
  const int wc = w & 1, wn = w >> 1;

  f32x4 acc[2][2];
  #pragma unroll
  for (int i = 0; i < 2; ++i)
    #pragma unroll
    for (int j = 0; j < 2; ++j) acc[i][j] = (f32x4){0.f, 0.f, 0.f, 0.f};

  for (int kt = 0; kt < 256; kt += 32) {
    __syncthreads();
    {
      int row = tid >> 2, seg = tid & 3;
      *(bf16x8*)&Al[row][seg * 8] = *(const bf16x8*)(Fb  + (size_t)(n0 + row) * 256 + kt + seg * 8);
      *(bf16x8*)&Wl[row][seg * 8] = *(const bf16x8*)(WpT + (size_t)(c0 + row) * 256 + kt + seg * 8);
    }
    __syncthreads();
    bf16x8 wf[2], xf[2];
    #pragma unroll
    for (int ci = 0; ci < 2; ++ci) wf[ci] = *(bf16x8*)&Wl[wc * 32 + ci * 16 + lr][lg * 8];
    #pragma unroll
    for (int ni = 0; ni < 2; ++ni) xf[ni] = *(bf16x8*)&Al[wn * 32 + ni * 16 + lr][lg * 8];
    #pragma unroll
    for (int ci = 0; ci < 2; ++ci)
      #pragma unroll
      for (int ni = 0; ni < 2; ++ni)
        acc[ci][ni] = __builtin_amdgcn_mfma_f32_16x16x32_bf16(wf[ci], xf[ni], acc[ci][ni], 0, 0, 0);
  }

  #pragma unroll
  for (int ci = 0; ci < 2; ++ci)
    #pragma unroll
    for (int ni = 0; ni < 2; ++ni) {
      int c = c0 + wc * 32 + ci * 16 + lg * 4;
      int n = n0 + wn * 32 + ni * 16 + lr;
      f32x4 bv = *(const f32x4*)(bias + c);
      f32x4 o = acc[ci][ni] + bv;
      *(f32x4*)(out + (size_t)n * 256 + c) = o;
    }
}

extern "C" void kernel_launch(void* const* d_in, const int* in_sizes, int n_in,
                              void* d_out, int out_size, void* d_ws, size_t ws_size,
                              hipStream_t stream) {
  (void)in_sizes; (void)n_in; (void)out_size; (void)ws_size;
  const float* qkv   = (const float*)d_in[0];
  const float* q_pos = (const float*)d_in[1];
  const int*   cu    = (const int*)d_in[2];
  const float* Wq    = (const float*)d_in[4];
  const float* Wkv   = (const float*)d_in[5];
  const float* Wproj = (const float*)d_in[6];
  const float* bproj = (const float*)d_in[7];
  float* out = (float*)d_out;

  const size_t M = (size_t)NTOK * CDIM;   // 1048576
  short* S    = (short*)d_ws;
  short* Xq   = S;
  short* X    = S + M;
  short* qb   = S + 2 * M;
  short* khp  = S + 3 * M;
  short* vblk = S + 4 * M;
  short* Fb   = S + 5 * M;
  short* WT   = S + 6 * M;
  short* WpT  = WT + 768 * 256;

  prep_kernel<<<1280, 256, 0, stream>>>(qkv, q_pos, Wq, Wkv, Wproj, Xq, X, WT, WpT);
  gemm_qkv<<<dim3(12, 64), 256, 0, stream>>>(Xq, X, WT, qb, khp, vblk);
  attn8<<<1024, 256, 0, stream>>>(qb, khp, vblk, cu, Fb);
  gemm_out<<<dim3(4, 64), 256, 0, stream>>>(Fb, WpT, bproj, out);
}